// Round 2
// baseline (364.086 us; speedup 1.0000x reference)
//
#include <hip/hip_runtime.h>
#include <stdint.h>

#define BS 8
#define LQ 256
#define HH 192
#define WW 192
#define HW (HH*WW)     /* 36864 */
#define KK 16

// ---------- helpers ----------

// monotone mapping: float -> uint32 preserving total order (no NaNs here)
__device__ __forceinline__ uint32_t fkey(float f) {
    uint32_t u = __float_as_uint(f);
    uint32_t mask = (uint32_t)((int32_t)u >> 31) | 0x80000000u;
    return u ^ mask;
}

__device__ __forceinline__ unsigned long long umin64(unsigned long long a, unsigned long long b) {
    return a < b ? a : b;
}

__device__ __forceinline__ unsigned long long wave_min_u64(unsigned long long v) {
    #pragma unroll
    for (int off = 32; off >= 1; off >>= 1) {
        uint32_t lo = (uint32_t)v, hi = (uint32_t)(v >> 32);
        lo = __shfl_xor(lo, off, 64);
        hi = __shfl_xor(hi, off, 64);
        unsigned long long o = ((unsigned long long)hi << 32) | lo;
        v = umin64(v, o);
    }
    return v;
}

__device__ __forceinline__ float wave_min_f32(float v) {
    #pragma unroll
    for (int off = 32; off >= 1; off >>= 1)
        v = fminf(v, __shfl_xor(v, off, 64));
    return v;
}

// stable sorted insert of (s,p) into ascending kkey/kidx[16].
// Strict '<' => equal keys placed after existing (arrival order = increasing
// pixel idx within a lane => exact (sim, idx) lexicographic order per lane).
__device__ __forceinline__ void insert_pair(float (&kkey)[KK], uint32_t (&kidx)[KK],
                                            float s, uint32_t p) {
    #pragma unroll
    for (int j = KK - 1; j >= 1; --j) {
        bool bjm1 = s < kkey[j - 1];
        bool bj   = s < kkey[j];
        kkey[j] = bjm1 ? kkey[j - 1] : (bj ? s : kkey[j]);
        kidx[j] = bjm1 ? kidx[j - 1] : (bj ? p : kidx[j]);
    }
    bool b0 = s < kkey[0];
    kkey[0] = b0 ? s : kkey[0];
    kidx[0] = b0 ? p : kidx[0];
}

// ---------- kernel 1: pack (c0,c1,c2,rsq) per pixel + pooled per (b,l) ----------
__global__ __launch_bounds__(256) void prep_kernel(const float* __restrict__ pred,
                                                   const float* __restrict__ ref,
                                                   float4* __restrict__ pix,
                                                   float4* __restrict__ pooled) {
    int g = blockIdx.x * 256 + threadIdx.x;       // 0 .. 73727 (294912/4 groups)
    int b = g / 9216;                             // 9216 float4-groups per image
    int v = g - b * 9216;
    const float4* c0p = (const float4*)(ref + (size_t)b * 3 * HW);
    float4 c0 = c0p[v];
    float4 c1 = c0p[v + 9216];
    float4 c2 = c0p[v + 18432];
    float4* o = pix + (size_t)b * HW + v * 4;
    {
        float r;
        r = __fadd_rn(__fadd_rn(__fmul_rn(c0.x, c0.x), __fmul_rn(c1.x, c1.x)), __fmul_rn(c2.x, c2.x));
        o[0] = make_float4(c0.x, c1.x, c2.x, r);
        r = __fadd_rn(__fadd_rn(__fmul_rn(c0.y, c0.y), __fmul_rn(c1.y, c1.y)), __fmul_rn(c2.y, c2.y));
        o[1] = make_float4(c0.y, c1.y, c2.y, r);
        r = __fadd_rn(__fadd_rn(__fmul_rn(c0.z, c0.z), __fmul_rn(c1.z, c1.z)), __fmul_rn(c2.z, c2.z));
        o[2] = make_float4(c0.z, c1.z, c2.z, r);
        r = __fadd_rn(__fadd_rn(__fmul_rn(c0.w, c0.w), __fmul_rn(c1.w, c1.w)), __fmul_rn(c2.w, c2.w));
        o[3] = make_float4(c0.w, c1.w, c2.w, r);
    }
    // pooled for the first 2048 threads (blocks 0..7)
    if (g < BS * LQ) {
        int t = g;                 // t = b*256 + l
        int bb = t >> 8;
        int l = t & 255;
        int i = l * BS + bb;       // scrambled flat grid row
        int b2 = i >> 8, l2 = i & 255;
        const float* pr = pred + ((b2 * 256 + l2) * 8);
        float x = pr[0], y = pr[1];
        float fx = rintf(__fsub_rn(__fmul_rn(x, 192.0f), 0.5f));
        float fy = rintf(__fsub_rn(__fmul_rn(y, 192.0f), 0.5f));
        int ix = (int)fx, iy = (int)fy;
        int inb = (ix >= 0 && ix < WW && iy >= 0 && iy < HH) ? 1 : 0;
        int ixc = min(max(ix, 0), WW - 1);
        int iyc = min(max(iy, 0), HH - 1);
        float m = (float)inb;
        const float* img = ref + bb * 3 * HW + iyc * WW + ixc;
        float p0 = __fmul_rn(img[0], m);
        float p1 = __fmul_rn(img[HW], m);
        float p2 = __fmul_rn(img[2 * HW], m);
        float psq = __fadd_rn(__fadd_rn(__fmul_rn(p0, p0), __fmul_rn(p1, p1)), __fmul_rn(p2, p2));
        pooled[t] = make_float4(p0, p1, p2, psq);
    }
}

// ---------- kernel 2: per-(b,l) top-16 smallest similar ----------
__device__ __forceinline__ void proc(float4 c, uint32_t p,
                                     float p0, float p1, float p2, float psq,
                                     float (&kkey)[KK], uint32_t (&kidx)[KK], float tau) {
    float cross = __fadd_rn(__fadd_rn(__fmul_rn(c.x, p0), __fmul_rn(c.y, p1)), __fmul_rn(c.z, p2));
    float sim   = __fadd_rn(__fsub_rn(c.w, __fmul_rn(2.0f, cross)), psq);
    if (sim <= tau) insert_pair(kkey, kidx, sim, p);   // <= : cross-lane ties at tau must survive
}

__global__ __launch_bounds__(256) void topk_kernel(const float4* __restrict__ pix,
                                                   const float4* __restrict__ pooled,
                                                   uint32_t* __restrict__ topk) {
    int bl = blockIdx.x;          // b*256 + l
    int b = bl >> 8;
    float4 pq = pooled[bl];
    const float4* img = pix + (size_t)b * HW;

    float    kkey[KK];
    uint32_t kidx[KK];
    #pragma unroll
    for (int j = 0; j < KK; ++j) { kkey[j] = __int_as_float(0x7f800000); kidx[j] = 0xFFFFFFFFu; }
    float tau = __int_as_float(0x7f800000);

    // 36864 px / (256 threads * 4 px) = 36 iterations
    for (int it = 0; it < HW / (256 * 4); ++it) {
        int base = (it * 256 + threadIdx.x) * 4;
        float4 a0 = img[base];
        float4 a1 = img[base + 1];
        float4 a2 = img[base + 2];
        float4 a3 = img[base + 3];
        proc(a0, base + 0, pq.x, pq.y, pq.z, pq.w, kkey, kidx, tau);
        proc(a1, base + 1, pq.x, pq.y, pq.z, pq.w, kkey, kidx, tau);
        proc(a2, base + 2, pq.x, pq.y, pq.z, pq.w, kkey, kidx, tau);
        proc(a3, base + 3, pq.x, pq.y, pq.z, pq.w, kkey, kidx, tau);
        if ((it & 1) == 1) tau = wave_min_f32(kkey[KK - 1]);   // sound: >= global 16th
    }

    // convert to exact u64 lexicographic keys (sim bits, pixel idx)
    unsigned long long kept[KK];
    #pragma unroll
    for (int j = 0; j < KK; ++j)
        kept[j] = ((unsigned long long)fkey(kkey[j]) << 32) | kidx[j];

    // --- wave-level merge: 16 rounds of min-pop ---
    __shared__ unsigned long long smerge[4 * KK];
    int wid = threadIdx.x >> 6;
    int lane = threadIdx.x & 63;
    #pragma unroll 1
    for (int r = 0; r < KK; ++r) {
        unsigned long long h = kept[0];
        unsigned long long m = wave_min_u64(h);
        if (h == m) {                          // unique key -> exactly one lane pops
            #pragma unroll
            for (int j = 0; j < KK - 1; ++j) kept[j] = kept[j + 1];
            kept[KK - 1] = ~0ull;
        }
        if (lane == 0) smerge[wid * KK + r] = m;
    }
    __syncthreads();

    // --- block-level 4-way merge, thread 0 ---
    if (threadIdx.x == 0) {
        int h0 = 0, h1 = 0, h2 = 0, h3 = 0;
        uint32_t* out = topk + (size_t)bl * KK;
        for (int r = 0; r < KK; ++r) {
            unsigned long long c0 = h0 < KK ? smerge[0 * KK + h0] : ~0ull;
            unsigned long long c1 = h1 < KK ? smerge[1 * KK + h1] : ~0ull;
            unsigned long long c2 = h2 < KK ? smerge[2 * KK + h2] : ~0ull;
            unsigned long long c3 = h3 < KK ? smerge[3 * KK + h3] : ~0ull;
            unsigned long long m = umin64(umin64(c0, c1), umin64(c2, c3));
            if (m == c0) h0++;
            else if (m == c1) h1++;
            else if (m == c2) h2++;
            else h3++;
            out[r] = (uint32_t)m;
        }
    }
}

// ---------- kernel 3: argmin over rolled targets + loss + mean (single block) ----------
__global__ __launch_bounds__(256) void loss_kernel(const float* __restrict__ pred,
                                                   const uint32_t* __restrict__ topk,
                                                   float* __restrict__ out) {
    double acc = 0.0;
    for (int b = 0; b < BS; ++b) {
        int t = b * 256 + threadIdx.x;
        int l = threadIdx.x;
        float px = pred[(size_t)t * 8 + 0];
        float py = pred[(size_t)t * 8 + 1];
        int lp = (l + LQ - 1) & (LQ - 1);      // roll(shift=1)
        const uint32_t* id = topk + ((size_t)(b * 256 + lp)) * KK;
        float best_d = __int_as_float(0x7f800000);
        float bx = 0.0f, by = 0.0f;
        #pragma unroll
        for (int k = 0; k < KK; ++k) {
            uint32_t idx = id[k];
            float tx = (float)(idx % WW) / 192.0f;
            float ty = (float)(idx / WW) / 192.0f;
            float dx = __fsub_rn(px, tx);
            float dy = __fsub_rn(py, ty);
            float d = __fadd_rn(__fmul_rn(dx, dx), __fmul_rn(dy, dy));
            if (d < best_d) { best_d = d; bx = tx; by = ty; }
        }
        if (l >= 1) {
            float ex = __fsub_rn(px, bx);
            float ey = __fsub_rn(py, by);
            acc += (double)__fadd_rn(__fmul_rn(ex, ex), __fmul_rn(ey, ey));
        }
    }
    __shared__ double sred[256];
    sred[threadIdx.x] = acc;
    __syncthreads();
    for (int s = 128; s > 0; s >>= 1) {
        if (threadIdx.x < s) sred[threadIdx.x] += sred[threadIdx.x + s];
        __syncthreads();
    }
    if (threadIdx.x == 0) out[0] = (float)(sred[0] / 2040.0);
}

// ---------- launch ----------
extern "C" void kernel_launch(void* const* d_in, const int* in_sizes, int n_in,
                              void* d_out, int out_size, void* d_ws, size_t ws_size,
                              hipStream_t stream) {
    const float* pred = (const float*)d_in[0];   // (8,256,8) f32
    const float* ref  = (const float*)d_in[1];   // (8,3,192,192) f32
    float* out = (float*)d_out;

    char* ws = (char*)d_ws;
    float4*   pix    = (float4*)ws;                                  // 294912*16B = 4.72 MB
    float4*   pooled = (float4*)(ws + (size_t)BS * HW * 16);         // 2048*16B
    uint32_t* topk   = (uint32_t*)(ws + (size_t)BS * HW * 16 + 2048 * 16);  // 128 KB

    prep_kernel<<<288, 256, 0, stream>>>(pred, ref, pix, pooled);
    topk_kernel<<<BS * LQ, 256, 0, stream>>>(pix, pooled, topk);
    loss_kernel<<<1, 256, 0, stream>>>(pred, topk, out);
}

// Round 3
// 170.266 us; speedup vs baseline: 2.1383x; 2.1383x over previous
//
#include <hip/hip_runtime.h>
#include <stdint.h>

#define BS 8
#define LQ 256
#define HH 192
#define WW 192
#define HW (HH*WW)     /* 36864 */
#define KK 16
#define QCAP 512       /* u64 entries per wave queue; drain when scnt >= QCAP-256 */

// ---------- helpers ----------

// monotone mapping: float -> uint32 preserving total order (no NaNs here)
__device__ __forceinline__ uint32_t fkey(float f) {
    uint32_t u = __float_as_uint(f);
    uint32_t mask = (uint32_t)((int32_t)u >> 31) | 0x80000000u;
    return u ^ mask;
}

__device__ __forceinline__ unsigned long long umin64(unsigned long long a, unsigned long long b) {
    return a < b ? a : b;
}

__device__ __forceinline__ unsigned long long wave_min_u64(unsigned long long v) {
    #pragma unroll
    for (int off = 32; off >= 1; off >>= 1) {
        uint32_t lo = (uint32_t)v, hi = (uint32_t)(v >> 32);
        lo = __shfl_xor(lo, off, 64);
        hi = __shfl_xor(hi, off, 64);
        unsigned long long o = ((unsigned long long)hi << 32) | lo;
        v = umin64(v, o);
    }
    return v;
}

// branchless sorted insert into ascending kept[16] of u64 keys (exact lex order)
__device__ __forceinline__ void insert64(unsigned long long (&kept)[KK], unsigned long long key) {
    #pragma unroll
    for (int j = KK - 1; j >= 1; --j) {
        unsigned long long a = kept[j - 1];
        unsigned long long mn = umin64(kept[j], key);
        kept[j] = (key < a) ? a : mn;
    }
    kept[0] = umin64(kept[0], key);
}

// tau (float domain) from wave-min of each lane's 16th-best key
__device__ __forceinline__ float tau_from_kept(unsigned long long (&kept)[KK]) {
    unsigned long long t = wave_min_u64(kept[KK - 1]);
    uint32_t v = (uint32_t)(t >> 32);
    uint32_t u = (v & 0x80000000u) ? (v ^ 0x80000000u) : ~v;   // inverse of fkey
    return __uint_as_float(u);
}

__device__ __forceinline__ float simf(float4 c, float4 pq) {
    float cross = __fadd_rn(__fadd_rn(__fmul_rn(c.x, pq.x), __fmul_rn(c.y, pq.y)), __fmul_rn(c.z, pq.z));
    return __fadd_rn(__fsub_rn(c.w, __fmul_rn(2.0f, cross)), pq.w);
}

// ---------- kernel 1: pack (c0,c1,c2,rsq) per pixel + pooled per (b,l) ----------
__global__ __launch_bounds__(256) void prep_kernel(const float* __restrict__ pred,
                                                   const float* __restrict__ ref,
                                                   float4* __restrict__ pix,
                                                   float4* __restrict__ pooled) {
    int g = blockIdx.x * 256 + threadIdx.x;       // 0 .. 73727 float4-groups
    int b = g / 9216;
    int v = g - b * 9216;
    const float4* c0p = (const float4*)(ref + (size_t)b * 3 * HW);
    float4 c0 = c0p[v];
    float4 c1 = c0p[v + 9216];
    float4 c2 = c0p[v + 18432];
    float4* o = pix + (size_t)b * HW + v * 4;
    {
        float r;
        r = __fadd_rn(__fadd_rn(__fmul_rn(c0.x, c0.x), __fmul_rn(c1.x, c1.x)), __fmul_rn(c2.x, c2.x));
        o[0] = make_float4(c0.x, c1.x, c2.x, r);
        r = __fadd_rn(__fadd_rn(__fmul_rn(c0.y, c0.y), __fmul_rn(c1.y, c1.y)), __fmul_rn(c2.y, c2.y));
        o[1] = make_float4(c0.y, c1.y, c2.y, r);
        r = __fadd_rn(__fadd_rn(__fmul_rn(c0.z, c0.z), __fmul_rn(c1.z, c1.z)), __fmul_rn(c2.z, c2.z));
        o[2] = make_float4(c0.z, c1.z, c2.z, r);
        r = __fadd_rn(__fadd_rn(__fmul_rn(c0.w, c0.w), __fmul_rn(c1.w, c1.w)), __fmul_rn(c2.w, c2.w));
        o[3] = make_float4(c0.w, c1.w, c2.w, r);
    }
    if (g < BS * LQ) {
        int t = g;                 // t = b*256 + l
        int bb = t >> 8;
        int l = t & 255;
        int i = l * BS + bb;       // scrambled flat grid row
        int b2 = i >> 8, l2 = i & 255;
        const float* pr = pred + ((b2 * 256 + l2) * 8);
        float x = pr[0], y = pr[1];
        float fx = rintf(__fsub_rn(__fmul_rn(x, 192.0f), 0.5f));
        float fy = rintf(__fsub_rn(__fmul_rn(y, 192.0f), 0.5f));
        int ix = (int)fx, iy = (int)fy;
        int inb = (ix >= 0 && ix < WW && iy >= 0 && iy < HH) ? 1 : 0;
        int ixc = min(max(ix, 0), WW - 1);
        int iyc = min(max(iy, 0), HH - 1);
        float m = (float)inb;
        const float* img = ref + bb * 3 * HW + iyc * WW + ixc;
        float p0 = __fmul_rn(img[0], m);
        float p1 = __fmul_rn(img[HW], m);
        float p2 = __fmul_rn(img[2 * HW], m);
        float psq = __fadd_rn(__fadd_rn(__fmul_rn(p0, p0), __fmul_rn(p1, p1)), __fmul_rn(p2, p2));
        pooled[t] = make_float4(p0, p1, p2, psq);
    }
}

// ---------- kernel 2: per-(b,l) top-16 via queue + batched drains ----------
__global__ __launch_bounds__(256) void topk_kernel(const float4* __restrict__ pix,
                                                   const float4* __restrict__ pooled,
                                                   uint32_t* __restrict__ topk) {
    __shared__ unsigned long long qbuf[4][QCAP];   // per-wave candidate queues (16 KB)
    __shared__ unsigned long long smerge[4 * KK];

    int bl = blockIdx.x;          // b*256 + l
    int b = bl >> 8;
    int lane = threadIdx.x & 63;
    int wid  = threadIdx.x >> 6;
    float4 pq = pooled[bl];
    const float4* img = pix + (size_t)b * HW;
    int wbase = wid * 9216;                        // wave's pixel range [wbase, wbase+9216)
    unsigned long long* qw = qbuf[wid];

    unsigned long long kept[KK];
    #pragma unroll
    for (int j = 0; j < KK; ++j) kept[j] = ~0ull;

    // ---- warm-up: first 4 sites (16 px/lane) direct branchless insert ----
    for (int it = 0; it < 4; ++it) {
        int base = wbase + it * 256 + lane * 4;
        float4 a0 = img[base], a1 = img[base + 1], a2 = img[base + 2], a3 = img[base + 3];
        float s0 = simf(a0, pq), s1 = simf(a1, pq), s2 = simf(a2, pq), s3 = simf(a3, pq);
        insert64(kept, ((unsigned long long)fkey(s0) << 32) | (uint32_t)(base + 0));
        insert64(kept, ((unsigned long long)fkey(s1) << 32) | (uint32_t)(base + 1));
        insert64(kept, ((unsigned long long)fkey(s2) << 32) | (uint32_t)(base + 2));
        insert64(kept, ((unsigned long long)fkey(s3) << 32) | (uint32_t)(base + 3));
    }

    // ---- pooled exact tau: true 16th smallest of first 1024 px (union of kept) ----
    float tau_f;
    {
        unsigned long long tmp[KK];
        #pragma unroll
        for (int j = 0; j < KK; ++j) tmp[j] = kept[j];
        unsigned long long m = 0;
        #pragma unroll 1
        for (int r = 0; r < KK; ++r) {
            m = wave_min_u64(tmp[0]);
            if (tmp[0] == m) {
                #pragma unroll
                for (int j = 0; j < KK - 1; ++j) tmp[j] = tmp[j + 1];
                tmp[KK - 1] = ~0ull;
            }
        }
        uint32_t v = (uint32_t)(m >> 32);
        uint32_t u = (v & 0x80000000u) ? (v ^ 0x80000000u) : ~v;
        tau_f = __uint_as_float(u);
    }

    // ---- main loop: cheap check + queue push; batched drains ----
    uint32_t scnt = 0;
    #pragma unroll 1
    for (int it = 4; it < 36; ++it) {
        int base = wbase + it * 256 + lane * 4;
        float4 a0 = img[base], a1 = img[base + 1], a2 = img[base + 2], a3 = img[base + 3];
        float s0 = simf(a0, pq), s1 = simf(a1, pq), s2 = simf(a2, pq), s3 = simf(a3, pq);

        #define PUSH(s, pidx)                                                            \
        {                                                                                \
            bool pass = (s) <= tau_f;   /* <= : ties at tau must survive */              \
            unsigned long long pm = __ballot(pass);                                      \
            if (pass) {                                                                  \
                uint32_t rank = __builtin_amdgcn_mbcnt_hi((uint32_t)(pm >> 32),          \
                                 __builtin_amdgcn_mbcnt_lo((uint32_t)pm, 0));            \
                qw[scnt + rank] = ((unsigned long long)fkey(s) << 32) | (uint32_t)(pidx);\
            }                                                                            \
            scnt += (uint32_t)__popcll(pm);                                              \
        }
        PUSH(s0, base + 0)
        PUSH(s1, base + 1)
        PUSH(s2, base + 2)
        PUSH(s3, base + 3)
        #undef PUSH

        if (scnt >= QCAP - 256) {          // next site adds at most 256 -> never overflows
            for (uint32_t e = lane; e < scnt; e += 64) insert64(kept, qw[e]);
            scnt = 0;
            tau_f = tau_from_kept(kept);
        }
    }
    // final drain
    for (uint32_t e = lane; e < scnt; e += 64) insert64(kept, qw[e]);

    // ---- wave-level merge: 16 rounds of min-pop ----
    #pragma unroll 1
    for (int r = 0; r < KK; ++r) {
        unsigned long long h = kept[0];
        unsigned long long m = wave_min_u64(h);
        if (h == m) {                      // keys unique -> exactly one lane pops
            #pragma unroll
            for (int j = 0; j < KK - 1; ++j) kept[j] = kept[j + 1];
            kept[KK - 1] = ~0ull;
        }
        if (lane == 0) smerge[wid * KK + r] = m;
    }
    __syncthreads();

    // ---- block-level 4-way merge, thread 0 ----
    if (threadIdx.x == 0) {
        int h0 = 0, h1 = 0, h2 = 0, h3 = 0;
        uint32_t* out = topk + (size_t)bl * KK;
        for (int r = 0; r < KK; ++r) {
            unsigned long long c0 = h0 < KK ? smerge[0 * KK + h0] : ~0ull;
            unsigned long long c1 = h1 < KK ? smerge[1 * KK + h1] : ~0ull;
            unsigned long long c2 = h2 < KK ? smerge[2 * KK + h2] : ~0ull;
            unsigned long long c3 = h3 < KK ? smerge[3 * KK + h3] : ~0ull;
            unsigned long long m = umin64(umin64(c0, c1), umin64(c2, c3));
            if (m == c0) h0++;
            else if (m == c1) h1++;
            else if (m == c2) h2++;
            else h3++;
            out[r] = (uint32_t)m;
        }
    }
}

// ---------- kernel 3: argmin over rolled targets + loss + mean (single block) ----------
__global__ __launch_bounds__(256) void loss_kernel(const float* __restrict__ pred,
                                                   const uint32_t* __restrict__ topk,
                                                   float* __restrict__ out) {
    double acc = 0.0;
    for (int b = 0; b < BS; ++b) {
        int t = b * 256 + threadIdx.x;
        int l = threadIdx.x;
        float px = pred[(size_t)t * 8 + 0];
        float py = pred[(size_t)t * 8 + 1];
        int lp = (l + LQ - 1) & (LQ - 1);      // roll(shift=1)
        const uint32_t* id = topk + ((size_t)(b * 256 + lp)) * KK;
        float best_d = __int_as_float(0x7f800000);
        float bx = 0.0f, by = 0.0f;
        #pragma unroll
        for (int k = 0; k < KK; ++k) {
            uint32_t idx = id[k];
            float tx = (float)(idx % WW) / 192.0f;
            float ty = (float)(idx / WW) / 192.0f;
            float dx = __fsub_rn(px, tx);
            float dy = __fsub_rn(py, ty);
            float d = __fadd_rn(__fmul_rn(dx, dx), __fmul_rn(dy, dy));
            if (d < best_d) { best_d = d; bx = tx; by = ty; }
        }
        if (l >= 1) {
            float ex = __fsub_rn(px, bx);
            float ey = __fsub_rn(py, by);
            acc += (double)__fadd_rn(__fmul_rn(ex, ex), __fmul_rn(ey, ey));
        }
    }
    __shared__ double sred[256];
    sred[threadIdx.x] = acc;
    __syncthreads();
    for (int s = 128; s > 0; s >>= 1) {
        if (threadIdx.x < s) sred[threadIdx.x] += sred[threadIdx.x + s];
        __syncthreads();
    }
    if (threadIdx.x == 0) out[0] = (float)(sred[0] / 2040.0);
}

// ---------- launch ----------
extern "C" void kernel_launch(void* const* d_in, const int* in_sizes, int n_in,
                              void* d_out, int out_size, void* d_ws, size_t ws_size,
                              hipStream_t stream) {
    const float* pred = (const float*)d_in[0];   // (8,256,8) f32
    const float* ref  = (const float*)d_in[1];   // (8,3,192,192) f32
    float* out = (float*)d_out;

    char* ws = (char*)d_ws;
    float4*   pix    = (float4*)ws;                                  // 294912*16B = 4.72 MB
    float4*   pooled = (float4*)(ws + (size_t)BS * HW * 16);         // 2048*16B
    uint32_t* topk   = (uint32_t*)(ws + (size_t)BS * HW * 16 + 2048 * 16);  // 128 KB

    prep_kernel<<<288, 256, 0, stream>>>(pred, ref, pix, pooled);
    topk_kernel<<<BS * LQ, 256, 0, stream>>>(pix, pooled, topk);
    loss_kernel<<<1, 256, 0, stream>>>(pred, topk, out);
}

// Round 4
// 146.829 us; speedup vs baseline: 2.4797x; 1.1596x over previous
//
#include <hip/hip_runtime.h>
#include <stdint.h>

#define BS 8
#define LQ 256
#define HH 192
#define WW 192
#define HW (HH*WW)     /* 36864 */
#define KK 16
#define QCAP 512       /* u64 entries per wave queue */
#define NSITES 144     /* HW / 256 px per site */

typedef unsigned long long u64;

// ---------- helpers ----------

// monotone mapping: float -> uint32 preserving total order (no NaNs here)
__device__ __forceinline__ uint32_t fkey(float f) {
    uint32_t u = __float_as_uint(f);
    uint32_t mask = (uint32_t)((int32_t)u >> 31) | 0x80000000u;
    return u ^ mask;
}
__device__ __forceinline__ float inv_fkey(uint32_t v) {
    uint32_t u = (v & 0x80000000u) ? (v ^ 0x80000000u) : ~v;
    return __uint_as_float(u);
}

__device__ __forceinline__ u64 umin64(u64 a, u64 b) { return a < b ? a : b; }

__device__ __forceinline__ u64 wave_min_u64(u64 v) {
    #pragma unroll
    for (int off = 32; off >= 1; off >>= 1) {
        uint32_t lo = (uint32_t)v, hi = (uint32_t)(v >> 32);
        lo = __shfl_xor(lo, off, 64);
        hi = __shfl_xor(hi, off, 64);
        u64 o = ((u64)hi << 32) | lo;
        v = umin64(v, o);
    }
    return v;
}

// branchless sorted insert into ascending kept[16] (exact u64 lex order)
__device__ __forceinline__ void insert64(u64 (&kept)[KK], u64 key) {
    #pragma unroll
    for (int j = KK - 1; j >= 1; --j) {
        u64 a = kept[j - 1];
        u64 mn = umin64(kept[j], key);
        kept[j] = (key < a) ? a : mn;
    }
    kept[0] = umin64(kept[0], key);
}

__device__ __forceinline__ float simf(float4 c, float4 pq) {
    float cross = __fadd_rn(__fadd_rn(__fmul_rn(c.x, pq.x), __fmul_rn(c.y, pq.y)), __fmul_rn(c.z, pq.z));
    return __fadd_rn(__fsub_rn(c.w, __fmul_rn(2.0f, cross)), pq.w);
}

// binary search in monotone key-bit space for tau with wave-cnt(kept<=tau) >= 16.
// Sound: hi is only lowered when count >= 16; initial hi covers all finite sims.
__device__ __forceinline__ uint32_t refine_tau(const u64 (&kept)[KK], uint32_t hi, int iters) {
    uint32_t khi[KK];
    #pragma unroll
    for (int j = 0; j < KK; ++j) khi[j] = (uint32_t)(kept[j] >> 32);
    uint32_t lo = 0x00800000u;             // fkey(-FLT_MAX): below all real sims
    #pragma unroll 1
    for (int t = 0; t < iters; ++t) {
        uint32_t mid = lo + ((hi - lo) >> 1);
        int c = 0;
        #pragma unroll
        for (int j = 0; j < KK; ++j) c += (khi[j] <= mid) ? 1 : 0;
        #pragma unroll
        for (int off = 32; off >= 1; off >>= 1) c += __shfl_xor(c, off, 64);
        if (c >= KK) hi = mid; else lo = mid + 1;
    }
    return hi;
}

// ---------- kernel 1: pack (c0,c1,c2,rsq) per pixel + pooled per (b,l) ----------
__global__ __launch_bounds__(256) void prep_kernel(const float* __restrict__ pred,
                                                   const float* __restrict__ ref,
                                                   float4* __restrict__ pix,
                                                   float4* __restrict__ pooled) {
    int g = blockIdx.x * 256 + threadIdx.x;       // 0 .. 73727 float4-groups
    int b = g / 9216;
    int v = g - b * 9216;
    const float4* c0p = (const float4*)(ref + (size_t)b * 3 * HW);
    float4 c0 = c0p[v];
    float4 c1 = c0p[v + 9216];
    float4 c2 = c0p[v + 18432];
    float4* o = pix + (size_t)b * HW + v * 4;
    {
        float r;
        r = __fadd_rn(__fadd_rn(__fmul_rn(c0.x, c0.x), __fmul_rn(c1.x, c1.x)), __fmul_rn(c2.x, c2.x));
        o[0] = make_float4(c0.x, c1.x, c2.x, r);
        r = __fadd_rn(__fadd_rn(__fmul_rn(c0.y, c0.y), __fmul_rn(c1.y, c1.y)), __fmul_rn(c2.y, c2.y));
        o[1] = make_float4(c0.y, c1.y, c2.y, r);
        r = __fadd_rn(__fadd_rn(__fmul_rn(c0.z, c0.z), __fmul_rn(c1.z, c1.z)), __fmul_rn(c2.z, c2.z));
        o[2] = make_float4(c0.z, c1.z, c2.z, r);
        r = __fadd_rn(__fadd_rn(__fmul_rn(c0.w, c0.w), __fmul_rn(c1.w, c1.w)), __fmul_rn(c2.w, c2.w));
        o[3] = make_float4(c0.w, c1.w, c2.w, r);
    }
    if (g < BS * LQ) {
        int t = g;                 // t = b*256 + l
        int bb = t >> 8;
        int l = t & 255;
        int i = l * BS + bb;       // scrambled flat grid row
        int b2 = i >> 8, l2 = i & 255;
        const float* pr = pred + ((b2 * 256 + l2) * 8);
        float x = pr[0], y = pr[1];
        float fx = rintf(__fsub_rn(__fmul_rn(x, 192.0f), 0.5f));
        float fy = rintf(__fsub_rn(__fmul_rn(y, 192.0f), 0.5f));
        int ix = (int)fx, iy = (int)fy;
        int inb = (ix >= 0 && ix < WW && iy >= 0 && iy < HH) ? 1 : 0;
        int ixc = min(max(ix, 0), WW - 1);
        int iyc = min(max(iy, 0), HH - 1);
        float m = (float)inb;
        const float* img = ref + bb * 3 * HW + iyc * WW + ixc;
        float p0 = __fmul_rn(img[0], m);
        float p1 = __fmul_rn(img[HW], m);
        float p2 = __fmul_rn(img[2 * HW], m);
        float psq = __fadd_rn(__fadd_rn(__fmul_rn(p0, p0), __fmul_rn(p1, p1)), __fmul_rn(p2, p2));
        pooled[t] = make_float4(p0, p1, p2, psq);
    }
}

// ---------- kernel 2: one WAVE per query; 4 queries per block ----------
__global__ __launch_bounds__(256) void topk_kernel(const float4* __restrict__ pix,
                                                   const float4* __restrict__ pooled,
                                                   uint32_t* __restrict__ topk) {
    __shared__ u64 qbuf[4][QCAP];   // per-wave candidate queue (16 KB)
    __shared__ u64 cbuf[4][64];     // per-wave compaction buffer (2 KB)

    int lane = threadIdx.x & 63;
    int wid  = threadIdx.x >> 6;
    // XCD swizzle: image b = blockIdx & 7 so each image's 64 blocks share one XCD's L2
    int b  = blockIdx.x & 7;
    int qg = blockIdx.x >> 3;            // 0..63
    int l  = qg * 4 + wid;               // 0..255
    int bl = b * 256 + l;

    float4 pq = pooled[bl];
    const float4* img = pix + (size_t)b * HW;
    u64* qw = qbuf[wid];

    // ---- warm-up: sites 0..3 (16 px/lane), bitonic-sort into kept ----
    u64 w[KK];
    #pragma unroll
    for (int it = 0; it < 4; ++it) {
        int base = it * 256 + lane * 4;
        float4 a0 = img[base], a1 = img[base + 1], a2 = img[base + 2], a3 = img[base + 3];
        w[it * 4 + 0] = ((u64)fkey(simf(a0, pq)) << 32) | (uint32_t)(base + 0);
        w[it * 4 + 1] = ((u64)fkey(simf(a1, pq)) << 32) | (uint32_t)(base + 1);
        w[it * 4 + 2] = ((u64)fkey(simf(a2, pq)) << 32) | (uint32_t)(base + 2);
        w[it * 4 + 3] = ((u64)fkey(simf(a3, pq)) << 32) | (uint32_t)(base + 3);
    }
    #pragma unroll
    for (int k = 2; k <= 16; k <<= 1) {
        #pragma unroll
        for (int j = k >> 1; j > 0; j >>= 1) {
            #pragma unroll
            for (int i = 0; i < 16; ++i) {
                int p = i ^ j;
                if (p > i) {
                    bool up = ((i & k) == 0);
                    u64 a = w[i], c = w[p];
                    bool sw = (a > c) == up;
                    w[i] = sw ? c : a;
                    w[p] = sw ? a : c;
                }
            }
        }
    }
    u64 kept[KK];
    #pragma unroll
    for (int j = 0; j < KK; ++j) kept[j] = w[j];

    // ---- tau: binary-refined bound on exact 16th of first 1024 px ----
    uint32_t tau_key = refine_tau(kept, 0xFF7FFFFFu, 12);
    float tau_f = inv_fkey(tau_key);

    // ---- main loop: sites 4..143, prefetch next site, site-level any-check ----
    uint32_t scnt = 0;
    int drains = 0;
    int nb0 = 4 * 256 + lane * 4;
    float4 n0 = img[nb0], n1 = img[nb0 + 1], n2 = img[nb0 + 2], n3 = img[nb0 + 3];

    #pragma unroll 1
    for (int it = 4; it < NSITES; ++it) {
        float4 c0 = n0, c1 = n1, c2 = n2, c3 = n3;
        int nxt = (it + 1 < NSITES ? it + 1 : it) * 256 + lane * 4;
        n0 = img[nxt]; n1 = img[nxt + 1]; n2 = img[nxt + 2]; n3 = img[nxt + 3];

        int base = it * 256 + lane * 4;
        float s0 = simf(c0, pq), s1 = simf(c1, pq), s2 = simf(c2, pq), s3 = simf(c3, pq);
        bool p0 = (s0 <= tau_f), p1 = (s1 <= tau_f), p2 = (s2 <= tau_f), p3 = (s3 <= tau_f);
        u64 anym = __ballot(p0 | p1 | p2 | p3);
        if (anym) {
            #define PUSH(pp, s, pidx)                                                        \
            {                                                                                \
                u64 pm = __ballot(pp);                                                       \
                if (pp) {                                                                    \
                    uint32_t rank = __builtin_amdgcn_mbcnt_hi((uint32_t)(pm >> 32),          \
                                     __builtin_amdgcn_mbcnt_lo((uint32_t)pm, 0));            \
                    qw[scnt + rank] = ((u64)fkey(s) << 32) | (uint32_t)(pidx);               \
                }                                                                            \
                scnt += (uint32_t)__popcll(pm);                                              \
            }
            PUSH(p0, s0, base + 0)
            PUSH(p1, s1, base + 1)
            PUSH(p2, s2, base + 2)
            PUSH(p3, s3, base + 3)
            #undef PUSH

            uint32_t thr = (drains < 2) ? 64u : 256u;   // tighten tau fast early
            if (scnt >= thr) {
                for (uint32_t e = lane; e < scnt; e += 64) insert64(kept, qw[e]);
                scnt = 0;
                drains++;
                tau_key = refine_tau(kept, tau_key, 8);  // old tau still sound upper bracket
                tau_f = inv_fkey(tau_key);
            }
        }
    }
    // final drain
    for (uint32_t e = lane; e < scnt; e += 64) insert64(kept, qw[e]);

    // ---- merge: compact entries <= tau (cnt >= 16 invariant) + rank-select ----
    int c = 0;
    #pragma unroll
    for (int j = 0; j < KK; ++j) c += ((uint32_t)(kept[j] >> 32) <= tau_key) ? 1 : 0;
    int pref = c;
    #pragma unroll
    for (int i = 1; i < 64; i <<= 1) {
        int t = __shfl_up(pref, i, 64);
        if (lane >= i) pref += t;
    }
    int M = __shfl(pref, 63, 64);
    int basec = pref - c;
    u64* cb = cbuf[wid];
    uint32_t* out = topk + (size_t)bl * KK;

    if (M <= 64) {
        #pragma unroll
        for (int j = 0; j < KK; ++j)
            if (j < c) cb[basec + j] = kept[j];     // kept sorted: first c are <= tau
    }
    __syncthreads();   // uniform: every wave reaches this exactly once
    if (M <= 64) {
        u64 my = (lane < M) ? cb[lane] : ~0ull;
        int rank = 0;
        #pragma unroll 1
        for (int m = 0; m < M; ++m) rank += (cb[m] < my) ? 1 : 0;
        if (lane < M && rank < KK) out[rank] = (uint32_t)my;
    } else {
        // fallback (should never trigger): exact 16-round min-pop
        #pragma unroll 1
        for (int r = 0; r < KK; ++r) {
            u64 m = wave_min_u64(kept[0]);
            if (kept[0] == m) {
                #pragma unroll
                for (int j = 0; j < KK - 1; ++j) kept[j] = kept[j + 1];
                kept[KK - 1] = ~0ull;
            }
            if (lane == 0) out[r] = (uint32_t)m;
        }
    }
}

// ---------- kernel 3: argmin over rolled targets + loss partials (8 blocks) ----------
__global__ __launch_bounds__(256) void loss_kernel(const float* __restrict__ pred,
                                                   const uint32_t* __restrict__ topk,
                                                   double* __restrict__ partial) {
    int t = blockIdx.x * 256 + threadIdx.x;   // t = b*256 + l
    int b = t >> 8;
    int l = t & 255;
    float px = pred[(size_t)t * 8 + 0];
    float py = pred[(size_t)t * 8 + 1];
    int lp = (l + LQ - 1) & (LQ - 1);         // roll(shift=1)
    const uint32_t* id = topk + ((size_t)(b * 256 + lp)) * KK;
    float best_d = __int_as_float(0x7f800000);
    float bx = 0.0f, by = 0.0f;
    #pragma unroll
    for (int k = 0; k < KK; ++k) {
        uint32_t idx = id[k];
        float tx = (float)(idx % WW) / 192.0f;
        float ty = (float)(idx / WW) / 192.0f;
        float dx = __fsub_rn(px, tx);
        float dy = __fsub_rn(py, ty);
        float d = __fadd_rn(__fmul_rn(dx, dx), __fmul_rn(dy, dy));
        if (d < best_d) { best_d = d; bx = tx; by = ty; }  // first-min = argmin
    }
    float term = 0.0f;
    if (l >= 1) {
        float ex = __fsub_rn(px, bx);
        float ey = __fsub_rn(py, by);
        term = __fadd_rn(__fmul_rn(ex, ex), __fmul_rn(ey, ey));
    }
    __shared__ double sred[256];
    sred[threadIdx.x] = (double)term;
    __syncthreads();
    for (int s = 128; s > 0; s >>= 1) {
        if (threadIdx.x < s) sred[threadIdx.x] += sred[threadIdx.x + s];
        __syncthreads();
    }
    if (threadIdx.x == 0) partial[blockIdx.x] = sred[0];
}

// ---------- kernel 4: finalize mean ----------
__global__ void finalize_kernel(const double* __restrict__ partial, float* __restrict__ out) {
    if (threadIdx.x == 0 && blockIdx.x == 0) {
        double s = 0.0;
        for (int i = 0; i < BS; ++i) s += partial[i];
        out[0] = (float)(s / 2040.0);   // mean over bs*(L-1) = 8*255
    }
}

// ---------- launch ----------
extern "C" void kernel_launch(void* const* d_in, const int* in_sizes, int n_in,
                              void* d_out, int out_size, void* d_ws, size_t ws_size,
                              hipStream_t stream) {
    const float* pred = (const float*)d_in[0];   // (8,256,8) f32
    const float* ref  = (const float*)d_in[1];   // (8,3,192,192) f32
    float* out = (float*)d_out;

    char* ws = (char*)d_ws;
    float4*   pix    = (float4*)ws;                                         // 4.72 MB
    float4*   pooled = (float4*)(ws + (size_t)BS * HW * 16);                // 32 KB
    uint32_t* topk   = (uint32_t*)(ws + (size_t)BS * HW * 16 + 2048 * 16);  // 128 KB
    double*   partial = (double*)(ws + (size_t)BS * HW * 16 + 2048 * 16 + 2048 * KK * 4);

    prep_kernel    <<<288, 256, 0, stream>>>(pred, ref, pix, pooled);
    topk_kernel    <<<512, 256, 0, stream>>>(pix, pooled, topk);
    loss_kernel    <<<BS, 256, 0, stream>>>(pred, topk, partial);
    finalize_kernel<<<1, 64, 0, stream>>>(partial, out);
}